// Round 13
// baseline (65.732 us; speedup 1.0000x reference)
//
#include <hip/hip_runtime.h>
#include <math.h>

// MaxofErosions2D, scalar-f32 + min3/max3, SGPR kernel taps, f-split passes.
// out[b,h,w,f] = max_c min_{dy,dx} ( x[b,h+dy-2,w+dx-2,c] - kern[4-dy,4-dx,c,f] )
// x: (32,256,256,3) f32, kern: (5,5,3,8) f32, out: (32,256,256,8) f32.
//
// Ledger-driven redesign (R3..R12): VOP3P (pk f16/i16) issues at 4 cy/wave64,
// plain f32 VOP at 2 cy -> packing saved no ALU time. Minimum issue slots =
// f32 with v_min3 folding: 600 sub + 360 min3 + 8 max3 per px (~26us busy).
// k taps are wave-uniform -> read from global with unrolled const offsets
// (s_load -> SGPR operand, free) — kills the 75-150/thread klds ds_reads
// that capped VALUBusy at ~60% in all LDS variants (R3 no-LDS hit 80%).
// f dimension split in 2 rolled passes: acc 48 VGPR/pass, ~16KB body (I$-fit).
// Block = 4 rows x 256 thr, thread = 4 px (best-known geometry). Exact f32.

#define Hq 256

__global__ __launch_bounds__(256) void maxero_f32(
    const float* __restrict__ x,
    const float* __restrict__ kern,
    float* __restrict__ out)
{
    __shared__ __align__(16) float xt[8 * 792];   // 8 rows x 264 cols x 3 ch, 25344 B

    const int tid = threadIdx.x;
    const int bI  = blockIdx.x;        // 2048 blocks
    const int b   = bI >> 6;           // image
    const int h0  = (bI & 63) << 2;    // first output row

    const float INF = __builtin_inff();

    // ---- stage x tile (f32): 1536 float4 chunks, 6/thread; halo = +inf
    const float* xb = x + (size_t)b * (Hq * 256 * 3);
    #pragma unroll
    for (int k = 0; k < 6; ++k) {
        int chunk = tid + k * 256;            // 0..1535
        int rr    = chunk / 192;              // 192 float4 per row
        int off   = (chunk - rr * 192) * 4;   // f32 offset in row interior
        int r     = h0 - 2 + rr;
        bool rv   = (unsigned)r < (unsigned)Hq;
        int rc    = min(max(r, 0), Hq - 1);
        float4 v = *reinterpret_cast<const float4*>(xb + rc * 768 + off);
        // interior f32 idx = rr*792 + 18 + off (18+off even -> two b64 writes)
        float2* d = reinterpret_cast<float2*>(&xt[rr * 792 + 18 + off]);
        d[0] = rv ? make_float2(v.x, v.y) : make_float2(INF, INF);
        d[1] = rv ? make_float2(v.z, v.w) : make_float2(INF, INF);
    }
    // halo: per row 18 left (cols -6..-1) + 6 right (cols 256,257)
    if (tid < 192) {
        int rr = tid / 24, p = tid - rr * 24;
        xt[rr * 792 + (p < 18 ? p : 768 + p)] = INF;
    }
    __syncthreads();

    const int hrow = tid >> 6;           // 0..3
    const int w0   = (tid & 63) << 2;    // 0..252
    const size_t rowbase = (size_t)b * 65536 + (size_t)(h0 + hrow) * 256 + w0;

    #pragma unroll 1                     // two f-half passes, rolled (I$)
    for (int fh = 0; fh < 2; ++fh) {
        const float* kub = kern + fh * 4;     // uniform base, s_load offsets const

        float acc[4][3][4];              // [px][c][j] -- all indices compile-time
        #pragma unroll
        for (int p = 0; p < 4; ++p)
            #pragma unroll
            for (int c = 0; c < 3; ++c)
                #pragma unroll
                for (int j = 0; j < 4; ++j)
                    acc[p][c][j] = INF;

        #pragma unroll
        for (int dy = 0; dy < 5; ++dy) {
            // 8 cols (w0-2..w0+5) x 3 ch = 24 contiguous f32, 16B-aligned
            const float4* rp = reinterpret_cast<const float4*>(
                &xt[(hrow + dy) * 792 + 12 + 3 * w0]);
            float xr[24];
            #pragma unroll
            for (int q = 0; q < 6; ++q) {
                float4 t = rp[q];
                xr[q * 4 + 0] = t.x; xr[q * 4 + 1] = t.y;
                xr[q * 4 + 2] = t.z; xr[q * 4 + 3] = t.w;
            }
            #pragma unroll
            for (int c = 0; c < 3; ++c)
                #pragma unroll
                for (int j = 0; j < 4; ++j) {
                    // 5 wave-uniform taps for this (dy,c,j): SGPR operands
                    float k0 = kub[((4 - dy) * 5 + 4) * 24 + c * 8 + j];
                    float k1 = kub[((4 - dy) * 5 + 3) * 24 + c * 8 + j];
                    float k2 = kub[((4 - dy) * 5 + 2) * 24 + c * 8 + j];
                    float k3 = kub[((4 - dy) * 5 + 1) * 24 + c * 8 + j];
                    float k4 = kub[((4 - dy) * 5 + 0) * 24 + c * 8 + j];
                    #pragma unroll
                    for (int p = 0; p < 4; ++p) {
                        float c0 = xr[(p + 0) * 3 + c] - k0;
                        float c1 = xr[(p + 1) * 3 + c] - k1;
                        float c2 = xr[(p + 2) * 3 + c] - k2;
                        float c3 = xr[(p + 3) * 3 + c] - k3;
                        float c4 = xr[(p + 4) * 3 + c] - k4;
                        float a = acc[p][c][j];
                        a = fminf(fminf(a, c0), c1);   // -> v_min3_f32
                        a = fminf(fminf(a, c2), c3);   // -> v_min3_f32
                        acc[p][c][j] = fminf(a, c4);
                    }
                }
        }

        // ---- epilogue: channel max3, store this f-half (float4/px, aligned)
        #pragma unroll
        for (int p = 0; p < 4; ++p) {
            float4 o;
            o.x = fmaxf(fmaxf(acc[p][0][0], acc[p][1][0]), acc[p][2][0]);
            o.y = fmaxf(fmaxf(acc[p][0][1], acc[p][1][1]), acc[p][2][1]);
            o.z = fmaxf(fmaxf(acc[p][0][2], acc[p][1][2]), acc[p][2][2]);
            o.w = fmaxf(fmaxf(acc[p][0][3], acc[p][1][3]), acc[p][2][3]);
            *reinterpret_cast<float4*>(out + (rowbase + p) * 8 + fh * 4) = o;
        }
    }
}

extern "C" void kernel_launch(void* const* d_in, const int* in_sizes, int n_in,
                              void* d_out, int out_size, void* d_ws, size_t ws_size,
                              hipStream_t stream) {
    const float* x    = (const float*)d_in[0];
    const float* kern = (const float*)d_in[1];
    float* out        = (float*)d_out;
    maxero_f32<<<2048, 256, 0, stream>>>(x, kern, out);  // 32 img x 64 row-groups
}

// Round 14
// 61.525 us; speedup vs baseline: 1.0684x; 1.0684x over previous
//
#include <hip/hip_runtime.h>
#include <math.h>

// MaxofErosions2D, two-kernel: pad+pack pre-pass -> barrier-light pk-f16 main.
// out[b,h,w,f] = max_c min_{dy,dx} ( x[b,h+dy-2,w+dx-2,c] - kern[4-dy,4-dx,c,f] )
// x: (32,256,256,3) f32, kern: (5,5,3,8) f32, out: (32,256,256,8) f32.
//
// Ledger facts (R3..R13): VOP3P pk(f16/i16) = 4 cy/wave64 (packing saves regs,
// not ALU); R11 busy 32us is the pk op-count floor; every LDS-staged variant
// caps at ~60% VALUBusy while the only no-LDS-chain kernel (R3) hit 80%.
// This round: move ALL padding/packing into a memory-bound pre-kernel writing
// d_ws (f16 pixel-pairs, channel-planar, inf halos, 13.2 MB). Main kernel hot
// loop = 30 coalesced dwordx2 loads (L2-resident via XCD swizzle) + R11's
// exact pk math + dup-k LDS broadcast. No x staging, no clamps, no cvts.

typedef _Float16 h2 __attribute__((ext_vector_type(2)));

static __device__ __forceinline__ h2 u2h(unsigned u) {
    return __builtin_bit_cast(h2, u);
}
static __device__ __forceinline__ unsigned packh(float a, float b) {
    return __builtin_bit_cast(unsigned, __builtin_amdgcn_cvt_pkrtz(a, b));
}

#define INF2 0x7C007C00u
#define PROW 132               // u32 pixel-pairs per padded row (cols -2..261)
#define PPLANE (260 * 132)     // u32 per (b,c) plane (rows -2..257)

// ---- pre-kernel: pad + f16-pair-pack x -> ws, layout [b][c][row+2][pair] ----
__global__ __launch_bounds__(256) void pad_pack(
    const float* __restrict__ x, unsigned* __restrict__ ws)
{
    const int tid = threadIdx.x;
    const int blk = blockIdx.x;
    if (blk < 2048) {
        // interior: 1 block = 4 rows of one image; thread = 4 px x 3 ch
        const int b = blk >> 6;
        const int r = ((blk & 63) << 2) + (tid >> 6);     // 0..255
        const int g = tid & 63;                           // col group: 4g..4g+3
        const float4* p = reinterpret_cast<const float4*>(
            x + ((size_t)b * 65536 + (size_t)r * 256 + 4 * g) * 3);
        float4 v0 = p[0], v1 = p[1], v2 = p[2];
        const float fv[12] = { v0.x, v0.y, v0.z, v0.w,
                               v1.x, v1.y, v1.z, v1.w,
                               v2.x, v2.y, v2.z, v2.w };
        #pragma unroll
        for (int c = 0; c < 3; ++c) {
            size_t idx = (size_t)(b * 3 + c) * PPLANE + (size_t)(r + 2) * PROW
                         + 2 * g + 1;                     // pairs 1..128
            ws[idx]     = packh(fv[c],     fv[3 + c]);
            ws[idx + 1] = packh(fv[6 + c], fv[9 + c]);
        }
    } else {
        // halo: 1 block per image. Per c: pad rows {0,1,258,259} full (528)
        // + interior rows 2..257 pairs {0,129} (512) = 1040; x3 c = 3120.
        const int b = blk - 2048;
        for (int i = tid; i < 3120; i += 256) {
            int c = i / 1040, rm = i - c * 1040;
            int row, idx;
            if (rm < 528) {
                int rr = rm / 132;
                row = (rr < 2) ? rr : rr + 256;           // 0,1,258,259
                idx = rm - rr * 132;
            } else {
                int t = rm - 528;
                row = 2 + (t >> 1);
                idx = (t & 1) ? 129 : 0;                  // cols 256,257 / -2,-1
            }
            ws[(size_t)(b * 3 + c) * PPLANE + (size_t)row * PROW + idx] = INF2;
        }
    }
}

// ---- main kernel: direct pre-packed loads + pk-f16 min-plus ----
__global__ __launch_bounds__(256) void maxero_direct(
    const unsigned* __restrict__ ws,
    const float* __restrict__ kern,
    float* __restrict__ out)
{
    __shared__ __align__(16) unsigned kd[600];   // [tap][c][f] = {k,k} dup pairs

    const int tid  = threadIdx.x;
    // XCD-bijective swizzle: 2048 = 8 x 256; each XCD gets 4 whole images
    // -> its ws slice (4 x 412 KB = 1.65 MB) fits the 4 MB XCD L2.
    const int orig = blockIdx.x;
    const int L    = (orig & 7) * 256 + (orig >> 3);
    const int b    = L >> 6;
    const int h0   = (L & 63) << 2;

    // stage dup'd pre-flipped kernel (600 > 256: strided!)
    for (int i = tid; i < 600; i += 256) {
        int tap = i / 24, rem = i - tap * 24;
        int c = rem >> 3, f = rem & 7;
        int dy = tap / 5, dx = tap - dy * 5;
        float v = kern[((4 - dy) * 5 + (4 - dx)) * 24 + c * 8 + f];
        kd[i] = packh(v, v);
    }
    __syncthreads();

    const int hrow = tid >> 6;           // 0..3
    const int w0   = (tid & 63) << 2;    // 0..252
    const int h    = h0 + hrow;          // padded row of tap dy = h + dy

    h2 e01[3][8], e23[3][8];             // pixel-pairs (w0,w0+1), (w0+2,w0+3)
    #pragma unroll
    for (int c = 0; c < 3; ++c)
        #pragma unroll
        for (int f = 0; f < 8; ++f) {
            e01[c][f] = u2h(INF2);
            e23[c][f] = u2h(INF2);
        }

    const unsigned* wb = ws + (size_t)b * 3 * PPLANE + (size_t)h * PROW + (w0 >> 1);

    #pragma unroll
    for (int dy = 0; dy < 5; ++dy) {
        // 4 aligned pairs (cols w0-2..w0+5) per channel + 3 shifted pairs
        unsigned a[3][4], mis[3][3];
        #pragma unroll
        for (int c = 0; c < 3; ++c) {
            const unsigned* rp = wb + (size_t)c * PPLANE + (size_t)dy * PROW;
            uint2 u0 = *reinterpret_cast<const uint2*>(rp);      // 8B-aligned
            uint2 u1 = *reinterpret_cast<const uint2*>(rp + 2);
            a[c][0] = u0.x; a[c][1] = u0.y; a[c][2] = u1.x; a[c][3] = u1.y;
            mis[c][0] = __builtin_amdgcn_alignbit(a[c][1], a[c][0], 16);
            mis[c][1] = __builtin_amdgcn_alignbit(a[c][2], a[c][1], 16);
            mis[c][2] = __builtin_amdgcn_alignbit(a[c][3], a[c][2], 16);
        }
        #pragma unroll
        for (int dx = 0; dx < 5; ++dx) {
            #pragma unroll
            for (int c = 0; c < 3; ++c) {
                h2 p01 = u2h((dx & 1) ? mis[c][dx >> 1]       : a[c][dx >> 1]);
                h2 p23 = u2h((dx & 1) ? mis[c][(dx >> 1) + 1] : a[c][(dx >> 1) + 1]);
                const uint4* kk = reinterpret_cast<const uint4*>(
                    &kd[(dy * 5 + dx) * 24 + c * 8]);
                uint4 k0 = kk[0], k1 = kk[1];   // broadcast, conflict-free
                const unsigned kf[8] = { k0.x, k0.y, k0.z, k0.w,
                                         k1.x, k1.y, k1.z, k1.w };
                #pragma unroll
                for (int f = 0; f < 8; ++f) {
                    e01[c][f] = __builtin_elementwise_min(e01[c][f], p01 - u2h(kf[f]));
                    e23[c][f] = __builtin_elementwise_min(e23[c][f], p23 - u2h(kf[f]));
                }
            }
        }
    }

    // epilogue: channel max, unpack pairs, f32 out, 8x float4
    float o0[8], o1[8], o2[8], o3[8];
    #pragma unroll
    for (int f = 0; f < 8; ++f) {
        h2 m01 = __builtin_elementwise_max(
                     __builtin_elementwise_max(e01[0][f], e01[1][f]), e01[2][f]);
        h2 m23 = __builtin_elementwise_max(
                     __builtin_elementwise_max(e23[0][f], e23[1][f]), e23[2][f]);
        o0[f] = (float)m01[0]; o1[f] = (float)m01[1];
        o2[f] = (float)m23[0]; o3[f] = (float)m23[1];
    }
    const size_t rowbase = (size_t)b * 65536 + (size_t)h * 256 + w0;
    float* op = out + rowbase * 8;
    reinterpret_cast<float4*>(op)[0] = make_float4(o0[0], o0[1], o0[2], o0[3]);
    reinterpret_cast<float4*>(op)[1] = make_float4(o0[4], o0[5], o0[6], o0[7]);
    reinterpret_cast<float4*>(op)[2] = make_float4(o1[0], o1[1], o1[2], o1[3]);
    reinterpret_cast<float4*>(op)[3] = make_float4(o1[4], o1[5], o1[6], o1[7]);
    reinterpret_cast<float4*>(op)[4] = make_float4(o2[0], o2[1], o2[2], o2[3]);
    reinterpret_cast<float4*>(op)[5] = make_float4(o2[4], o2[5], o2[6], o2[7]);
    reinterpret_cast<float4*>(op)[6] = make_float4(o3[0], o3[1], o3[2], o3[3]);
    reinterpret_cast<float4*>(op)[7] = make_float4(o3[4], o3[5], o3[6], o3[7]);
}

extern "C" void kernel_launch(void* const* d_in, const int* in_sizes, int n_in,
                              void* d_out, int out_size, void* d_ws, size_t ws_size,
                              hipStream_t stream) {
    const float* x    = (const float*)d_in[0];
    const float* kern = (const float*)d_in[1];
    float* out        = (float*)d_out;
    unsigned* ws      = (unsigned*)d_ws;       // needs 32*3*260*132*4 = 13.2 MB
    pad_pack<<<2080, 256, 0, stream>>>(x, ws);
    maxero_direct<<<2048, 256, 0, stream>>>(ws, kern, out);
}

// Round 15
// 56.013 us; speedup vs baseline: 1.1735x; 1.0984x over previous
//
#include <hip/hip_runtime.h>
#include <math.h>

// MaxofErosions2D, pk-f16 pixel-pairs, ROLLED-dy hot loop (I$-resident body).
// out[b,h,w,f] = max_c min_{dy,dx} ( x[b,h+dy-2,w+dx-2,c] - kern[4-dy,4-dx,c,f] )
// x: (32,256,256,3) f32, kern: (5,5,3,8) f32, out: (32,256,256,8) f32.
//
// R15 discriminating experiment vs R11 (op count IDENTICAL): roll the dy loop
// so the hot body shrinks ~21KB -> ~4KB. Ledger across R3..R14 shows the only
// >=75% VALUBusy kernel (R3) is the only one with body <=16KB; all ~21KB+
// fully-unrolled variants cap at 55-60% regardless of staging style, barriers,
// conflicts, occupancy, granularity -> I-cache fetch-stall hypothesis.
// Also: k stored as NATURAL f16 pairs (R9==R11 busy proves splat folds to
// op_sel, zero VALU cost) -> k LDS reads halve to 75 b128/thread.

typedef _Float16 h2 __attribute__((ext_vector_type(2)));

static __device__ __forceinline__ h2 u2h(unsigned u) {
    return __builtin_bit_cast(h2, u);
}
static __device__ __forceinline__ unsigned packh(float a, float b) {
    return __builtin_bit_cast(unsigned, __builtin_amdgcn_cvt_pkrtz(a, b));
}

#define Hq 256
#define RST 132             // u32 pixel-pairs per plane row: cols -2..261
#define PST (8 * RST)       // 1056 u32 per channel plane (8 tile rows)
#define TILE_U (3 * PST)    // 3168 u32 = 12672 B
#define INF2 0x7C007C00u    // +inf f16 pair

__global__ __launch_bounds__(256) void maxero_r15(
    const float* __restrict__ x,
    const float* __restrict__ kern,
    float* __restrict__ out)
{
    __shared__ __align__(16) unsigned xp[TILE_U];
    __shared__ __align__(16) unsigned kd[300];   // [tap][c][fp] NATURAL pairs

    const int tid = threadIdx.x;
    const int bI  = blockIdx.x;        // 2048 blocks
    const int b   = bI >> 6;           // image
    const int h0  = (bI & 63) << 2;    // first output row

    // ---- stage natural-pair pre-flipped kernel (300 > 256: strided!)
    for (int i = tid; i < 300; i += 256) {
        int tap = i / 12, rem = i - tap * 12;
        int c = rem >> 2, fp = rem & 3;
        int dy = tap / 5, dx = tap - dy * 5;
        const float* kp = kern + ((4 - dy) * 5 + (4 - dx)) * 24 + c * 8 + fp * 2;
        kd[i] = packh(kp[0], kp[1]);
    }

    // ---- stage x planar: 512 groups of 3 float4 (= 4 pixels x 3ch), 2/thread
    const float* xb = x + (size_t)b * (Hq * 256 * 3);
    #pragma unroll
    for (int k = 0; k < 2; ++k) {
        int g   = tid + k * 256;          // 0..511
        int rr  = g >> 6;                 // tile row 0..7
        int pg  = g & 63;                 // pixel group: cols 4pg..4pg+3
        int r   = h0 - 2 + rr;
        bool rv = (unsigned)r < (unsigned)Hq;
        int rc  = min(max(r, 0), Hq - 1);
        const float4* gp = reinterpret_cast<const float4*>(xb + rc * 768 + pg * 12);
        float4 v0 = gp[0], v1 = gp[1], v2 = gp[2];
        const float fv[12] = { v0.x, v0.y, v0.z, v0.w,
                               v1.x, v1.y, v1.z, v1.w,
                               v2.x, v2.y, v2.z, v2.w };
        int base = rr * RST + 2 * pg + 1;          // u32 idx of (cols 4pg,4pg+1)
        #pragma unroll
        for (int c = 0; c < 3; ++c) {
            xp[c * PST + base + 0] = rv ? packh(fv[c],     fv[3 + c]) : INF2;
            xp[c * PST + base + 1] = rv ? packh(fv[6 + c], fv[9 + c]) : INF2;
        }
    }
    // halo: per (c,row): u32 idx 0 (cols -2,-1) and 129 (cols 256,257)
    if (tid < 48) {
        int c = tid >> 4, rem = tid & 15;
        int rr = rem >> 1, side = rem & 1;
        xp[c * PST + rr * RST + (side ? 129 : 0)] = INF2;
    }
    __syncthreads();

    const int hrow = tid >> 6;           // 0..3
    const int w0   = (tid & 63) << 2;    // 0..252

    h2 e01[3][8], e23[3][8];             // pixel-pairs (w0,w0+1) and (w0+2,w0+3)
    #pragma unroll
    for (int c = 0; c < 3; ++c)
        #pragma unroll
        for (int f = 0; f < 8; ++f) {
            e01[c][f] = u2h(INF2);
            e23[c][f] = u2h(INF2);
        }

    #pragma unroll 1      // ROLLED: body ~4KB, I$-resident (the experiment)
    for (int dy = 0; dy < 5; ++dy) {
        // per channel: 4 aligned pairs (cols w0-2..w0+5) + 3 shifted pairs
        unsigned a[3][4], mis[3][3];
        #pragma unroll
        for (int c = 0; c < 3; ++c) {
            const unsigned* xr = &xp[c * PST + (hrow + dy) * RST + (w0 >> 1)];
            uint2 u0 = *reinterpret_cast<const uint2*>(xr);      // 8B-aligned
            uint2 u1 = *reinterpret_cast<const uint2*>(xr + 2);
            a[c][0] = u0.x; a[c][1] = u0.y; a[c][2] = u1.x; a[c][3] = u1.y;
            mis[c][0] = __builtin_amdgcn_alignbit(a[c][1], a[c][0], 16);
            mis[c][1] = __builtin_amdgcn_alignbit(a[c][2], a[c][1], 16);
            mis[c][2] = __builtin_amdgcn_alignbit(a[c][3], a[c][2], 16);
        }
        #pragma unroll
        for (int dx = 0; dx < 5; ++dx) {
            #pragma unroll
            for (int c = 0; c < 3; ++c) {
                // pixel pairs for this tap
                h2 p01 = u2h((dx & 1) ? mis[c][dx >> 1]       : a[c][dx >> 1]);
                h2 p23 = u2h((dx & 1) ? mis[c][(dx >> 1) + 1] : a[c][(dx >> 1) + 1]);
                // natural k pairs: 1 b128 per (tap,c), broadcast
                uint4 kq = *reinterpret_cast<const uint4*>(
                    &kd[(dy * 5 + dx) * 12 + c * 4]);
                const unsigned kn[4] = { kq.x, kq.y, kq.z, kq.w };
                #pragma unroll
                for (int fp = 0; fp < 4; ++fp) {
                    h2 kk = u2h(kn[fp]);
                    h2 klo = { kk[0], kk[0] };   // folds to op_sel (R9 evidence)
                    h2 khi = { kk[1], kk[1] };
                    e01[c][2*fp]   = __builtin_elementwise_min(e01[c][2*fp],   p01 - klo);
                    e23[c][2*fp]   = __builtin_elementwise_min(e23[c][2*fp],   p23 - klo);
                    e01[c][2*fp+1] = __builtin_elementwise_min(e01[c][2*fp+1], p01 - khi);
                    e23[c][2*fp+1] = __builtin_elementwise_min(e23[c][2*fp+1], p23 - khi);
                }
            }
        }
    }

    // ---- epilogue: channel max, unpack pairs, f32 out, 8x float4
    float o0[8], o1[8], o2[8], o3[8];
    #pragma unroll
    for (int f = 0; f < 8; ++f) {
        h2 m01 = __builtin_elementwise_max(
                     __builtin_elementwise_max(e01[0][f], e01[1][f]), e01[2][f]);
        h2 m23 = __builtin_elementwise_max(
                     __builtin_elementwise_max(e23[0][f], e23[1][f]), e23[2][f]);
        o0[f] = (float)m01[0]; o1[f] = (float)m01[1];
        o2[f] = (float)m23[0]; o3[f] = (float)m23[1];
    }
    const size_t rowbase = (size_t)b * 65536 + (size_t)(h0 + hrow) * 256 + w0;
    float* op = out + rowbase * 8;
    reinterpret_cast<float4*>(op)[0] = make_float4(o0[0], o0[1], o0[2], o0[3]);
    reinterpret_cast<float4*>(op)[1] = make_float4(o0[4], o0[5], o0[6], o0[7]);
    reinterpret_cast<float4*>(op)[2] = make_float4(o1[0], o1[1], o1[2], o1[3]);
    reinterpret_cast<float4*>(op)[3] = make_float4(o1[4], o1[5], o1[6], o1[7]);
    reinterpret_cast<float4*>(op)[4] = make_float4(o2[0], o2[1], o2[2], o2[3]);
    reinterpret_cast<float4*>(op)[5] = make_float4(o2[4], o2[5], o2[6], o2[7]);
    reinterpret_cast<float4*>(op)[6] = make_float4(o3[0], o3[1], o3[2], o3[3]);
    reinterpret_cast<float4*>(op)[7] = make_float4(o3[4], o3[5], o3[6], o3[7]);
}

extern "C" void kernel_launch(void* const* d_in, const int* in_sizes, int n_in,
                              void* d_out, int out_size, void* d_ws, size_t ws_size,
                              hipStream_t stream) {
    const float* x    = (const float*)d_in[0];
    const float* kern = (const float*)d_in[1];
    float* out        = (float*)d_out;
    maxero_r15<<<2048, 256, 0, stream>>>(x, kern, out);  // 32 img x 64 row-groups
}